// Round 1
// 363.523 us; speedup vs baseline: 1.3731x; 1.3731x over previous
//
#include <hip/hip_runtime.h>
#include <stdint.h>

typedef unsigned long long u64;
typedef float nfloat4 __attribute__((ext_vector_type(4)));  // native vec for nt-store

#define LQ   4096
#define BQ   8
#define KNB  16
#define LPQ  8                  // lanes per query
#define TPB  256
#define QPB  (TPB / LPQ)        // 32 queries per block
#define BPB  (LQ / QPB)         // 128 blocks per batch

__device__ __forceinline__ double dmin(double a, double b) { return __builtin_fmin(a, b); }
__device__ __forceinline__ double dmax(double a, double b) { return __builtin_fmax(a, b); }

// Keys are ((u64)f32bits(d2) << 12) | j  with d2 >= 0  =>  bit patterns < 2^43,
// i.e. positive f64 denormals. u64 ordering == f64 ordering for these, and f64
// denormals are never flushed on CDNA. Sentinel 1.0 is larger than any key.

__global__ __launch_bounds__(TPB) void knn_fused_kernel(
    const float4* __restrict__ frame4,   // (B, L, 3) float4 view of (B,L,4,3)
    const float4* __restrict__ attr4,    // (B, L, 32) float4 view of (B,L,128)
    float* __restrict__ out_e,           // (B, L, 16, 3)
    nfloat4* __restrict__ outg4)         // (B, L, 16, 32) float4
{
    __shared__ float4 cpos[LQ];          // 64 KB: all centers of this batch (w = R00)
    __shared__ int nbrs[QPB * KNB];      // 2 KB: per-block neighbor indices

    const int b    = blockIdx.x >> 7;    // 128 blocks per batch
    const int qblk = blockIdx.x & (BPB - 1);
    const int tid  = threadIdx.x;

    const float4* fb = frame4 + (size_t)b * LQ * 3;
    for (int j = tid; j < LQ; j += TPB) cpos[j] = fb[j * 3];
    __syncthreads();

    const int qloc = tid >> 3;           // 0..31
    const int h    = tid & 7;            // candidate sub-stream
    const int l    = qblk * QPB + qloc;  // within-batch query index
    const float4 me = cpos[l];

    // running sorted-ascending top-16 of keys, held as f64 bit patterns
    double R[KNB];
#pragma unroll
    for (int i = 0; i < KNB; ++i) R[i] = 1.0;   // sentinel > any denormal key

#pragma unroll 1
    for (int bb = 0; bb < 32; ++bb) {
        // --- compute 16 candidate keys (lane h covers j = 128*bb + 8*t + h) ---
        double S[KNB];
#pragma unroll
        for (int t = 0; t < 16; ++t) {
            const int j = bb * 128 + t * 8 + h;
            const float4 p = cpos[j];
            // bit-exact vs numpy: no FMA contraction, sum order (x^2+y^2)+z^2
            const float dx = __fsub_rn(me.x, p.x);
            const float dy = __fsub_rn(me.y, p.y);
            const float dz = __fsub_rn(me.z, p.z);
            const float d  = __fadd_rn(__fadd_rn(__fmul_rn(dx, dx), __fmul_rn(dy, dy)),
                                       __fmul_rn(dz, dz));
            const u64 key = ((u64)__float_as_uint(d) << 12) | (unsigned)j;
            S[t] = __builtin_bit_cast(double, key);
        }
        // --- bitonic sort S ascending; CE = v_min_f64 + v_max_f64 ---
#pragma unroll
        for (int k = 2; k <= 16; k <<= 1) {
#pragma unroll
            for (int g = k >> 1; g >= 1; g >>= 1) {
#pragma unroll
                for (int i = 0; i < 16; ++i) {
                    if ((i & g) == 0) {
                        const int j2 = i + g;
                        const bool up = ((i & k) == 0);
                        const double lo = dmin(S[i], S[j2]);
                        const double hi = dmax(S[i], S[j2]);
                        S[i]  = up ? lo : hi;
                        S[j2] = up ? hi : lo;
                    }
                }
            }
        }
        // --- merge: 16 smallest of (R asc, S asc) -> R asc ---
        double M[KNB];
#pragma unroll
        for (int i = 0; i < 16; ++i) M[i] = dmin(R[i], S[15 - i]);  // bitonic
#pragma unroll
        for (int g = 8; g >= 1; g >>= 1) {
#pragma unroll
            for (int i = 0; i < 16; ++i) {
                if ((i & g) == 0) {
                    const double lo = dmin(M[i], M[i + g]);
                    const double hi = dmax(M[i], M[i + g]);
                    M[i]     = lo;
                    M[i + g] = hi;
                }
            }
        }
#pragma unroll
        for (int i = 0; i < 16; ++i) R[i] = M[i];
    }

    // --- cross-lane merge over the 8 sub-streams (xor 1,2,4) ---
#pragma unroll
    for (int m = 1; m <= 4; m <<= 1) {
        double P[KNB];
#pragma unroll
        for (int i = 0; i < 16; ++i) P[i] = __shfl_xor(R[i], m, 64);
        double M[KNB];
#pragma unroll
        for (int i = 0; i < 16; ++i) M[i] = dmin(R[i], P[15 - i]);
#pragma unroll
        for (int g = 8; g >= 1; g >>= 1) {
#pragma unroll
            for (int i = 0; i < 16; ++i) {
                if ((i & g) == 0) {
                    const double lo = dmin(M[i], M[i + g]);
                    const double hi = dmax(M[i], M[i + g]);
                    M[i]     = lo;
                    M[i + g] = hi;
                }
            }
        }
#pragma unroll
        for (int i = 0; i < 16; ++i) R[i] = M[i];
    }

    if (h == 0) {
        const size_t gq = (size_t)b * LQ + l;
        const float4 f1 = fb[l * 3 + 1];
        const float4 f2 = fb[l * 3 + 2];
        const float R00 = me.w, R01 = f1.x, R02 = f1.y;
        const float R10 = f1.z, R11 = f1.w, R12 = f2.x;
        const float R20 = f2.y, R21 = f2.z, R22 = f2.w;

        float ebuf[48];
#pragma unroll
        for (int k = 0; k < KNB; ++k) {
            const u64 bits = __builtin_bit_cast(u64, R[k]);
            const int j = (int)(bits & 0xFFFu);
            nbrs[qloc * KNB + k] = j;
            const float4 p = cpos[j];
            const float dx = p.x - me.x;   // delta = nbr_center - center
            const float dy = p.y - me.y;
            const float dz = p.z - me.z;
            ebuf[k * 3 + 0] = dx * R00 + dy * R10 + dz * R20;
            ebuf[k * 3 + 1] = dx * R01 + dy * R11 + dz * R21;
            ebuf[k * 3 + 2] = dx * R02 + dy * R12 + dz * R22;
        }
        float4* eo = (float4*)(out_e + gq * 48);
#pragma unroll
        for (int t = 0; t < 12; ++t) eo[t] = ((const float4*)ebuf)[t];
    }

    // --- cooperative fused gather: 32 queries x 16 nbrs x 32 float4 = 16384 ---
    __syncthreads();
    const float4* ab = attr4 + (((size_t)b) << 12) * 32;     // this batch's attr
    const size_t obase = ((size_t)b * LQ + (size_t)qblk * QPB) * (KNB * 32);
#pragma unroll 8
    for (int it = 0; it < 64; ++it) {
        const int fl   = it * TPB + tid;     // 0 .. 16383
        const int d4   = fl & 31;            // float4 within D=128
        const int pair = fl >> 5;            // qloc*16 + k
        const int nb   = nbrs[pair];         // LDS broadcast across 32 lanes
        const float4 t4 = ab[(size_t)nb * 32 + d4];
        nfloat4 v = {t4.x, t4.y, t4.z, t4.w};
        __builtin_nontemporal_store(v, &outg4[obase + fl]);
    }
}

extern "C" void kernel_launch(void* const* d_in, const int* in_sizes, int n_in,
                              void* d_out, int out_size, void* d_ws, size_t ws_size,
                              hipStream_t stream)
{
    const float* frame = (const float*)d_in[0];   // (8,4096,4,3) f32
    const float* attr  = (const float*)d_in[1];   // (8,4096,128) f32
    float* out = (float*)d_out;                   // euclidian (1572864) ++ gathered (67108864)

    nfloat4* outg4 = (nfloat4*)(out + (size_t)BQ * LQ * KNB * 3);
    knn_fused_kernel<<<BQ * BPB, TPB, 0, stream>>>(
        (const float4*)frame, (const float4*)attr, out, outg4);
}

// Round 2
// 329.121 us; speedup vs baseline: 1.5166x; 1.1045x over previous
//
#include <hip/hip_runtime.h>
#include <stdint.h>

typedef unsigned long long u64;
typedef float nfloat4 __attribute__((ext_vector_type(4)));  // native vec for nt-store

#define LQ   4096
#define BQ   8
#define KNB  16
#define TPB  256
#define QPB  32                  // queries per block, 8 lanes each
#define BPB  (LQ / QPB)          // 128 blocks per batch

// u32 compare-exchange (full-rate v_min_u32/v_max_u32)
__device__ __forceinline__ void ceu(uint32_t &a, uint32_t &b) {
    const uint32_t mn = a < b ? a : b;
    const uint32_t mx = a < b ? b : a;
    a = mn; b = mx;
}
// f64 compare-exchange (exact 44-bit keys as positive denormals)
__device__ __forceinline__ void ced(double &a, double &b) {
    const double mn = __builtin_fmin(a, b);
    const double mx = __builtin_fmax(a, b);
    a = mn; b = mx;
}
// bit-exact vs reference: no FMA, sum order (x^2+y^2)+z^2
__device__ __forceinline__ float dist2(float mx, float my, float mz,
                                       float px, float py, float pz) {
    const float dx = __fsub_rn(mx, px);
    const float dy = __fsub_rn(my, py);
    const float dz = __fsub_rn(mz, pz);
    return __fadd_rn(__fadd_rn(__fmul_rn(dx, dx), __fmul_rn(dy, dy)),
                     __fmul_rn(dz, dz));
}

// Scan key: (f32 dist bits truncated to top 20) << 12 | j.  Monotone in d, so a
// true top-16 member has <=15 strictly-smaller keys + ~0.01 expected "bucket
// mates" (same 2^-11-relative bucket, smaller j). Keeping per-query top-32
// makes a wrong drop require >=17 mates (prob ~0); the 32 survivors are
// re-ranked exactly with the proven ((u64)d_bits<<12)|j keys.

__global__ __launch_bounds__(TPB) void knn_fused_kernel(
    const float4* __restrict__ frame4,   // (B, L, 3) float4 view of (B,L,4,3)
    const float4* __restrict__ attr4,    // (B, L, 32) float4 view of (B,L,128)
    float* __restrict__ out_e,           // (B, L, 16, 3)
    nfloat4* __restrict__ outg4)         // (B, L, 16, 32) float4
{
    __shared__ float xs[LQ], ys[LQ], zs[LQ];   // 48 KB (SoA -> 3 blocks/CU)
    __shared__ unsigned short surv[QPB][32];   // 2 KB  per-query top-32 cand idx
    __shared__ int nbrs[QPB][KNB];             // 2 KB  final neighbor idx

    const int b    = blockIdx.x >> 7;
    const int qblk = blockIdx.x & (BPB - 1);
    const int tid  = threadIdx.x;

    const float4* fb = frame4 + (size_t)b * LQ * 3;
    for (int j = tid; j < LQ; j += TPB) {
        const float4 v = fb[j * 3];
        xs[j] = v.x; ys[j] = v.y; zs[j] = v.z;
    }
    __syncthreads();   // only barrier: waves are independent afterwards

    const int qloc = tid >> 3;           // 0..31
    const int h    = tid & 7;            // sub-stream within query
    const int l    = qblk * QPB + qloc;
    const float mx = xs[l], my = ys[l], mz = zs[l];

    // per-lane running sorted-ascending top-16 of 32-bit keys
    uint32_t R[16];
#pragma unroll
    for (int i = 0; i < 16; ++i) R[i] = 0xFFFFFFFFu;

#pragma unroll 1
    for (int cc = 0; cc < 64; ++cc) {
        uint32_t K[8];
#pragma unroll
        for (int s = 0; s < 8; ++s) {
            const int j = cc * 64 + s * 8 + h;
            const float d = dist2(mx, my, mz, xs[j], ys[j], zs[j]);
            K[s] = (__float_as_uint(d) & 0xFFFFF000u) | (unsigned)j;
        }
        // Batcher odd-even mergesort-8 (19 comparators), ascending
        ceu(K[0],K[1]); ceu(K[2],K[3]); ceu(K[4],K[5]); ceu(K[6],K[7]);
        ceu(K[0],K[2]); ceu(K[1],K[3]); ceu(K[4],K[6]); ceu(K[5],K[7]);
        ceu(K[1],K[2]); ceu(K[5],K[6]);
        ceu(K[0],K[4]); ceu(K[1],K[5]); ceu(K[2],K[6]); ceu(K[3],K[7]);
        ceu(K[2],K[4]); ceu(K[3],K[5]);
        ceu(K[1],K[2]); ceu(K[3],K[4]); ceu(K[5],K[6]);
        // bottom-16 of (R asc-16 ∪ K asc-8): min-layer then bitonic merge-16
#pragma unroll
        for (int t = 0; t < 8; ++t) {
            const uint32_t x = R[8 + t], y = K[7 - t];
            R[8 + t] = x < y ? x : y;
        }
#pragma unroll
        for (int g = 8; g >= 1; g >>= 1)
#pragma unroll
            for (int i = 0; i < 16; ++i)
                if ((i & g) == 0) ceu(R[i], R[i + g]);
    }

    // ---- distributed cross-lane merge over the query's 8 lanes, keeping ALL
    // 128 elements: after this, position p = h*16+i is fully sorted ascending.
    // Round 1: (0|1),(2|3),... sorted-16+16 -> sorted-32
    {
        uint32_t P[16];
#pragma unroll
        for (int i = 0; i < 16; ++i) P[i] = __shfl_xor(R[i], 1, 64);
        const bool lo = (h & 1) == 0;
#pragma unroll
        for (int i = 0; i < 16; ++i) {
            const uint32_t o = P[15 - i];
            R[i] = lo ? (R[i] < o ? R[i] : o) : (R[i] > o ? R[i] : o);
        }
#pragma unroll
        for (int g = 8; g >= 1; g >>= 1)
#pragma unroll
            for (int i = 0; i < 16; ++i)
                if ((i & g) == 0) ceu(R[i], R[i + g]);
    }
    // Round 2: sorted-32+32 -> sorted-64 (xor3 reversed, xor1 same-reg, local)
    {
        uint32_t P[16];
#pragma unroll
        for (int i = 0; i < 16; ++i) P[i] = __shfl_xor(R[i], 3, 64);
        const bool lo = (h & 2) == 0;
#pragma unroll
        for (int i = 0; i < 16; ++i) {
            const uint32_t o = P[15 - i];
            R[i] = lo ? (R[i] < o ? R[i] : o) : (R[i] > o ? R[i] : o);
        }
#pragma unroll
        for (int i = 0; i < 16; ++i) P[i] = __shfl_xor(R[i], 1, 64);
        const bool lo1 = (h & 1) == 0;
#pragma unroll
        for (int i = 0; i < 16; ++i) {
            const uint32_t o = P[i];
            R[i] = lo1 ? (R[i] < o ? R[i] : o) : (R[i] > o ? R[i] : o);
        }
#pragma unroll
        for (int g = 8; g >= 1; g >>= 1)
#pragma unroll
            for (int i = 0; i < 16; ++i)
                if ((i & g) == 0) ceu(R[i], R[i + g]);
    }
    // Round 3: sorted-64+64 -> sorted-128 (xor7 rev, xor2, xor1, local)
    {
        uint32_t P[16];
#pragma unroll
        for (int i = 0; i < 16; ++i) P[i] = __shfl_xor(R[i], 7, 64);
        const bool lo = (h & 4) == 0;
#pragma unroll
        for (int i = 0; i < 16; ++i) {
            const uint32_t o = P[15 - i];
            R[i] = lo ? (R[i] < o ? R[i] : o) : (R[i] > o ? R[i] : o);
        }
#pragma unroll
        for (int i = 0; i < 16; ++i) P[i] = __shfl_xor(R[i], 2, 64);
        const bool lo2 = (h & 2) == 0;
#pragma unroll
        for (int i = 0; i < 16; ++i) {
            const uint32_t o = P[i];
            R[i] = lo2 ? (R[i] < o ? R[i] : o) : (R[i] > o ? R[i] : o);
        }
#pragma unroll
        for (int i = 0; i < 16; ++i) P[i] = __shfl_xor(R[i], 1, 64);
        const bool lo1 = (h & 1) == 0;
#pragma unroll
        for (int i = 0; i < 16; ++i) {
            const uint32_t o = P[i];
            R[i] = lo1 ? (R[i] < o ? R[i] : o) : (R[i] > o ? R[i] : o);
        }
#pragma unroll
        for (int g = 8; g >= 1; g >>= 1)
#pragma unroll
            for (int i = 0; i < 16; ++i)
                if ((i & g) == 0) ceu(R[i], R[i + g]);
    }

    // lanes 0,1 hold the query's top-32 keys -> publish candidate indices
    if (h < 2) {
#pragma unroll
        for (int i = 0; i < 16; ++i)
            surv[qloc][h * 16 + i] = (unsigned short)(R[i] & 0xFFFu);
    }

    // ---- exact re-rank of the 32 survivors with 44-bit keys (f64 denormals).
    // 4 keys per lane; distributed bitonic merge to sorted-32 over 8 lanes.
    double kd[4];
#pragma unroll
    for (int s = 0; s < 4; ++s) {
        const int j = surv[qloc][h * 4 + s];
        const float d = dist2(mx, my, mz, xs[j], ys[j], zs[j]);
        kd[s] = __builtin_bit_cast(double,
                 ((u64)__float_as_uint(d) << 12) | (unsigned)j);
    }
    // local sort-4 ascending
    ced(kd[0],kd[1]); ced(kd[2],kd[3]); ced(kd[0],kd[2]); ced(kd[1],kd[3]); ced(kd[1],kd[2]);
    // Round 1: xor1 reversed + local merge-4
    {
        double P[4];
#pragma unroll
        for (int s = 0; s < 4; ++s) P[s] = __shfl_xor(kd[s], 1, 64);
        const bool lo = (h & 1) == 0;
#pragma unroll
        for (int s = 0; s < 4; ++s) {
            const double o = P[3 - s];
            kd[s] = lo ? __builtin_fmin(kd[s], o) : __builtin_fmax(kd[s], o);
        }
        ced(kd[0],kd[2]); ced(kd[1],kd[3]); ced(kd[0],kd[1]); ced(kd[2],kd[3]);
    }
    // Round 2: xor3 rev, xor1 same, local
    {
        double P[4];
#pragma unroll
        for (int s = 0; s < 4; ++s) P[s] = __shfl_xor(kd[s], 3, 64);
        const bool lo = (h & 2) == 0;
#pragma unroll
        for (int s = 0; s < 4; ++s) {
            const double o = P[3 - s];
            kd[s] = lo ? __builtin_fmin(kd[s], o) : __builtin_fmax(kd[s], o);
        }
#pragma unroll
        for (int s = 0; s < 4; ++s) P[s] = __shfl_xor(kd[s], 1, 64);
        const bool lo1 = (h & 1) == 0;
#pragma unroll
        for (int s = 0; s < 4; ++s) {
            const double o = P[s];
            kd[s] = lo1 ? __builtin_fmin(kd[s], o) : __builtin_fmax(kd[s], o);
        }
        ced(kd[0],kd[2]); ced(kd[1],kd[3]); ced(kd[0],kd[1]); ced(kd[2],kd[3]);
    }
    // Round 3: xor7 rev, xor2 same, xor1 same, local
    {
        double P[4];
#pragma unroll
        for (int s = 0; s < 4; ++s) P[s] = __shfl_xor(kd[s], 7, 64);
        const bool lo = (h & 4) == 0;
#pragma unroll
        for (int s = 0; s < 4; ++s) {
            const double o = P[3 - s];
            kd[s] = lo ? __builtin_fmin(kd[s], o) : __builtin_fmax(kd[s], o);
        }
#pragma unroll
        for (int s = 0; s < 4; ++s) P[s] = __shfl_xor(kd[s], 2, 64);
        const bool lo2 = (h & 2) == 0;
#pragma unroll
        for (int s = 0; s < 4; ++s) {
            const double o = P[s];
            kd[s] = lo2 ? __builtin_fmin(kd[s], o) : __builtin_fmax(kd[s], o);
        }
#pragma unroll
        for (int s = 0; s < 4; ++s) P[s] = __shfl_xor(kd[s], 1, 64);
        const bool lo1 = (h & 1) == 0;
#pragma unroll
        for (int s = 0; s < 4; ++s) {
            const double o = P[s];
            kd[s] = lo1 ? __builtin_fmin(kd[s], o) : __builtin_fmax(kd[s], o);
        }
        ced(kd[0],kd[2]); ced(kd[1],kd[3]); ced(kd[0],kd[1]); ced(kd[2],kd[3]);
    }

    // lanes h<4 hold final top-16 (position h*4+s): epilogue
    const size_t gq = (size_t)b * LQ + l;
    if (h < 4) {
        const float4 f0 = fb[l * 3 + 0];
        const float4 f1 = fb[l * 3 + 1];
        const float4 f2 = fb[l * 3 + 2];
        const float R00 = f0.w, R01 = f1.x, R02 = f1.y;
        const float R10 = f1.z, R11 = f1.w, R12 = f2.x;
        const float R20 = f2.y, R21 = f2.z, R22 = f2.w;
        float e[12];
#pragma unroll
        for (int s = 0; s < 4; ++s) {
            const u64 bits = __builtin_bit_cast(u64, kd[s]);
            const int j = (int)(bits & 0xFFFu);
            nbrs[qloc][h * 4 + s] = j;
            const float dx = xs[j] - mx;      // delta = nbr_center - center
            const float dy = ys[j] - my;
            const float dz = zs[j] - mz;
            e[s * 3 + 0] = dx * R00 + dy * R10 + dz * R20;
            e[s * 3 + 1] = dx * R01 + dy * R11 + dz * R21;
            e[s * 3 + 2] = dx * R02 + dy * R12 + dz * R22;
        }
        float4* eo = (float4*)(out_e + gq * 48 + h * 12);
        float4 v0 = {e[0], e[1], e[2],  e[3]};
        float4 v1 = {e[4], e[5], e[6],  e[7]};
        float4 v2 = {e[8], e[9], e[10], e[11]};
        eo[0] = v0; eo[1] = v1; eo[2] = v2;
    }

    // ---- fused gather (per wave: its 8 queries x 16 nbrs x 32 float4) ----
    const float4* ab = attr4 + (((size_t)b) << 12) * 32;
    const int wv = tid >> 6, lane = tid & 63;
    const size_t obase = ((size_t)b * LQ + (size_t)qblk * QPB + (size_t)wv * 8) * 512;
#pragma unroll 4
    for (int it = 0; it < 64; ++it) {
        const int idx = it * 64 + lane;      // 0..4095
        const int qw  = idx >> 9;            // 0..7 within-wave query
        const int r   = idx & 511;
        const int k   = r >> 5, d4 = r & 31;
        const int nb  = nbrs[wv * 8 + qw][k];
        const float4 v = ab[(size_t)nb * 32 + d4];
        nfloat4 nv = {v.x, v.y, v.z, v.w};
        __builtin_nontemporal_store(nv, &outg4[obase + idx]);
    }
}

extern "C" void kernel_launch(void* const* d_in, const int* in_sizes, int n_in,
                              void* d_out, int out_size, void* d_ws, size_t ws_size,
                              hipStream_t stream)
{
    const float* frame = (const float*)d_in[0];   // (8,4096,4,3) f32
    const float* attr  = (const float*)d_in[1];   // (8,4096,128) f32
    float* out = (float*)d_out;                   // euclidian ++ gathered

    nfloat4* outg4 = (nfloat4*)(out + (size_t)BQ * LQ * KNB * 3);
    knn_fused_kernel<<<BQ * BPB, TPB, 0, stream>>>(
        (const float4*)frame, (const float4*)attr, out, outg4);
}

// Round 3
// 329.042 us; speedup vs baseline: 1.5169x; 1.0002x over previous
//
#include <hip/hip_runtime.h>
#include <stdint.h>

typedef unsigned long long u64;
typedef float nfloat4 __attribute__((ext_vector_type(4)));  // native vec for nt-store

#define LQ   4096
#define BQ   8
#define KNB  16
#define TPB  512
#define QPB  64                  // queries per block, 8 lanes each
#define BPB  (LQ / QPB)          // 64 blocks per batch

// u32 compare-exchange (full-rate v_min_u32/v_max_u32)
__device__ __forceinline__ void ceu(uint32_t &a, uint32_t &b) {
    const uint32_t mn = a < b ? a : b;
    const uint32_t mx = a < b ? b : a;
    a = mn; b = mx;
}
// f64 compare-exchange (exact 44-bit keys as positive denormals)
__device__ __forceinline__ void ced(double &a, double &b) {
    const double mn = __builtin_fmin(a, b);
    const double mx = __builtin_fmax(a, b);
    a = mn; b = mx;
}
// bit-exact vs reference: no FMA, sum order (x^2+y^2)+z^2
__device__ __forceinline__ float dist2(float mx, float my, float mz,
                                       float px, float py, float pz) {
    const float dx = __fsub_rn(mx, px);
    const float dy = __fsub_rn(my, py);
    const float dz = __fsub_rn(mz, pz);
    return __fadd_rn(__fadd_rn(__fmul_rn(dx, dx), __fmul_rn(dy, dy)),
                     __fmul_rn(dz, dz));
}

// Scan key: (f32 dist bits truncated to top 20) << 12 | j.  Monotone in d, so a
// true top-16 member has <=15 strictly-smaller keys + ~0.01 expected "bucket
// mates" (same 2^-11-relative bucket, smaller j). Keeping per-query top-32
// makes a wrong drop require >=17 mates (prob ~0); the 32 survivors are
// re-ranked exactly with the proven ((u64)d_bits<<12)|j keys.

__global__ __launch_bounds__(TPB) void knn_fused_kernel(
    const float4* __restrict__ frame4,   // (B, L, 3) float4 view of (B,L,4,3)
    const float4* __restrict__ attr4,    // (B, L, 32) float4 view of (B,L,128)
    float* __restrict__ out_e,           // (B, L, 16, 3)
    nfloat4* __restrict__ outg4)         // (B, L, 16, 32) float4
{
    __shared__ float xs[LQ], ys[LQ], zs[LQ];   // 48 KB (SoA)
    __shared__ unsigned short surv[QPB][32];   // 4 KB  per-query top-32 cand idx
    __shared__ int nbrs[QPB][KNB];             // 4 KB  final neighbor idx
    // total 56 KB -> exactly 2 blocks/CU, grid 512 = 2*256: zero tail

    const int b    = blockIdx.x >> 6;          // 64 blocks per batch
    const int qblk = blockIdx.x & (BPB - 1);
    const int tid  = threadIdx.x;

    const float4* fb = frame4 + (size_t)b * LQ * 3;
    for (int j = tid; j < LQ; j += TPB) {
        const float4 v = fb[j * 3];
        xs[j] = v.x; ys[j] = v.y; zs[j] = v.z;
    }
    __syncthreads();   // only barrier: waves are independent afterwards

    const int qloc = tid >> 3;           // 0..63
    const int h    = tid & 7;            // sub-stream within query
    const int l    = qblk * QPB + qloc;
    const float mx = xs[l], my = ys[l], mz = zs[l];

    // per-lane running sorted-ascending top-16 of 32-bit keys
    uint32_t R[16];
#pragma unroll
    for (int i = 0; i < 16; ++i) R[i] = 0xFFFFFFFFu;

#pragma unroll 1
    for (int cc = 0; cc < 64; ++cc) {
        uint32_t K[8];
#pragma unroll
        for (int s = 0; s < 8; ++s) {
            const int j = cc * 64 + s * 8 + h;
            const float d = dist2(mx, my, mz, xs[j], ys[j], zs[j]);
            K[s] = (__float_as_uint(d) & 0xFFFFF000u) | (unsigned)j;
        }
        // Batcher odd-even mergesort-8 (19 comparators), ascending
        ceu(K[0],K[1]); ceu(K[2],K[3]); ceu(K[4],K[5]); ceu(K[6],K[7]);
        ceu(K[0],K[2]); ceu(K[1],K[3]); ceu(K[4],K[6]); ceu(K[5],K[7]);
        ceu(K[1],K[2]); ceu(K[5],K[6]);
        ceu(K[0],K[4]); ceu(K[1],K[5]); ceu(K[2],K[6]); ceu(K[3],K[7]);
        ceu(K[2],K[4]); ceu(K[3],K[5]);
        ceu(K[1],K[2]); ceu(K[3],K[4]); ceu(K[5],K[6]);
        // bottom-16 of (R asc-16 ∪ K asc-8): min-layer then bitonic merge-16
#pragma unroll
        for (int t = 0; t < 8; ++t) {
            const uint32_t x = R[8 + t], y = K[7 - t];
            R[8 + t] = x < y ? x : y;
        }
#pragma unroll
        for (int g = 8; g >= 1; g >>= 1)
#pragma unroll
            for (int i = 0; i < 16; ++i)
                if ((i & g) == 0) ceu(R[i], R[i + g]);
    }

    // ---- distributed cross-lane merge over the query's 8 lanes, keeping ALL
    // 128 elements: after this, position p = h*16+i is fully sorted ascending.
    // Round 1: (0|1),(2|3),... sorted-16+16 -> sorted-32
    {
        uint32_t P[16];
#pragma unroll
        for (int i = 0; i < 16; ++i) P[i] = __shfl_xor(R[i], 1, 64);
        const bool lo = (h & 1) == 0;
#pragma unroll
        for (int i = 0; i < 16; ++i) {
            const uint32_t o = P[15 - i];
            R[i] = lo ? (R[i] < o ? R[i] : o) : (R[i] > o ? R[i] : o);
        }
#pragma unroll
        for (int g = 8; g >= 1; g >>= 1)
#pragma unroll
            for (int i = 0; i < 16; ++i)
                if ((i & g) == 0) ceu(R[i], R[i + g]);
    }
    // Round 2: sorted-32+32 -> sorted-64 (xor3 reversed, xor1 same-reg, local)
    {
        uint32_t P[16];
#pragma unroll
        for (int i = 0; i < 16; ++i) P[i] = __shfl_xor(R[i], 3, 64);
        const bool lo = (h & 2) == 0;
#pragma unroll
        for (int i = 0; i < 16; ++i) {
            const uint32_t o = P[15 - i];
            R[i] = lo ? (R[i] < o ? R[i] : o) : (R[i] > o ? R[i] : o);
        }
#pragma unroll
        for (int i = 0; i < 16; ++i) P[i] = __shfl_xor(R[i], 1, 64);
        const bool lo1 = (h & 1) == 0;
#pragma unroll
        for (int i = 0; i < 16; ++i) {
            const uint32_t o = P[i];
            R[i] = lo1 ? (R[i] < o ? R[i] : o) : (R[i] > o ? R[i] : o);
        }
#pragma unroll
        for (int g = 8; g >= 1; g >>= 1)
#pragma unroll
            for (int i = 0; i < 16; ++i)
                if ((i & g) == 0) ceu(R[i], R[i + g]);
    }
    // Round 3: sorted-64+64 -> sorted-128 (xor7 rev, xor2, xor1, local)
    {
        uint32_t P[16];
#pragma unroll
        for (int i = 0; i < 16; ++i) P[i] = __shfl_xor(R[i], 7, 64);
        const bool lo = (h & 4) == 0;
#pragma unroll
        for (int i = 0; i < 16; ++i) {
            const uint32_t o = P[15 - i];
            R[i] = lo ? (R[i] < o ? R[i] : o) : (R[i] > o ? R[i] : o);
        }
#pragma unroll
        for (int i = 0; i < 16; ++i) P[i] = __shfl_xor(R[i], 2, 64);
        const bool lo2 = (h & 2) == 0;
#pragma unroll
        for (int i = 0; i < 16; ++i) {
            const uint32_t o = P[i];
            R[i] = lo2 ? (R[i] < o ? R[i] : o) : (R[i] > o ? R[i] : o);
        }
#pragma unroll
        for (int i = 0; i < 16; ++i) P[i] = __shfl_xor(R[i], 1, 64);
        const bool lo1 = (h & 1) == 0;
#pragma unroll
        for (int i = 0; i < 16; ++i) {
            const uint32_t o = P[i];
            R[i] = lo1 ? (R[i] < o ? R[i] : o) : (R[i] > o ? R[i] : o);
        }
#pragma unroll
        for (int g = 8; g >= 1; g >>= 1)
#pragma unroll
            for (int i = 0; i < 16; ++i)
                if ((i & g) == 0) ceu(R[i], R[i + g]);
    }

    // lanes 0,1 hold the query's top-32 keys -> publish candidate indices
    if (h < 2) {
#pragma unroll
        for (int i = 0; i < 16; ++i)
            surv[qloc][h * 16 + i] = (unsigned short)(R[i] & 0xFFFu);
    }

    // ---- exact re-rank of the 32 survivors with 44-bit keys (f64 denormals).
    // 4 keys per lane; distributed bitonic merge to sorted-32 over 8 lanes.
    double kd[4];
#pragma unroll
    for (int s = 0; s < 4; ++s) {
        const int j = surv[qloc][h * 4 + s];
        const float d = dist2(mx, my, mz, xs[j], ys[j], zs[j]);
        kd[s] = __builtin_bit_cast(double,
                 ((u64)__float_as_uint(d) << 12) | (unsigned)j);
    }
    // local sort-4 ascending
    ced(kd[0],kd[1]); ced(kd[2],kd[3]); ced(kd[0],kd[2]); ced(kd[1],kd[3]); ced(kd[1],kd[2]);
    // Round 1: xor1 reversed + local merge-4
    {
        double P[4];
#pragma unroll
        for (int s = 0; s < 4; ++s) P[s] = __shfl_xor(kd[s], 1, 64);
        const bool lo = (h & 1) == 0;
#pragma unroll
        for (int s = 0; s < 4; ++s) {
            const double o = P[3 - s];
            kd[s] = lo ? __builtin_fmin(kd[s], o) : __builtin_fmax(kd[s], o);
        }
        ced(kd[0],kd[2]); ced(kd[1],kd[3]); ced(kd[0],kd[1]); ced(kd[2],kd[3]);
    }
    // Round 2: xor3 rev, xor1 same, local
    {
        double P[4];
#pragma unroll
        for (int s = 0; s < 4; ++s) P[s] = __shfl_xor(kd[s], 3, 64);
        const bool lo = (h & 2) == 0;
#pragma unroll
        for (int s = 0; s < 4; ++s) {
            const double o = P[3 - s];
            kd[s] = lo ? __builtin_fmin(kd[s], o) : __builtin_fmax(kd[s], o);
        }
#pragma unroll
        for (int s = 0; s < 4; ++s) P[s] = __shfl_xor(kd[s], 1, 64);
        const bool lo1 = (h & 1) == 0;
#pragma unroll
        for (int s = 0; s < 4; ++s) {
            const double o = P[s];
            kd[s] = lo1 ? __builtin_fmin(kd[s], o) : __builtin_fmax(kd[s], o);
        }
        ced(kd[0],kd[2]); ced(kd[1],kd[3]); ced(kd[0],kd[1]); ced(kd[2],kd[3]);
    }
    // Round 3: xor7 rev, xor2 same, xor1 same, local
    {
        double P[4];
#pragma unroll
        for (int s = 0; s < 4; ++s) P[s] = __shfl_xor(kd[s], 7, 64);
        const bool lo = (h & 4) == 0;
#pragma unroll
        for (int s = 0; s < 4; ++s) {
            const double o = P[3 - s];
            kd[s] = lo ? __builtin_fmin(kd[s], o) : __builtin_fmax(kd[s], o);
        }
#pragma unroll
        for (int s = 0; s < 4; ++s) P[s] = __shfl_xor(kd[s], 2, 64);
        const bool lo2 = (h & 2) == 0;
#pragma unroll
        for (int s = 0; s < 4; ++s) {
            const double o = P[s];
            kd[s] = lo2 ? __builtin_fmin(kd[s], o) : __builtin_fmax(kd[s], o);
        }
#pragma unroll
        for (int s = 0; s < 4; ++s) P[s] = __shfl_xor(kd[s], 1, 64);
        const bool lo1 = (h & 1) == 0;
#pragma unroll
        for (int s = 0; s < 4; ++s) {
            const double o = P[s];
            kd[s] = lo1 ? __builtin_fmin(kd[s], o) : __builtin_fmax(kd[s], o);
        }
        ced(kd[0],kd[2]); ced(kd[1],kd[3]); ced(kd[0],kd[1]); ced(kd[2],kd[3]);
    }

    // lanes h<4 hold final top-16 (position h*4+s): epilogue
    const size_t gq = (size_t)b * LQ + l;
    if (h < 4) {
        const float4 f0 = fb[l * 3 + 0];
        const float4 f1 = fb[l * 3 + 1];
        const float4 f2 = fb[l * 3 + 2];
        const float R00 = f0.w, R01 = f1.x, R02 = f1.y;
        const float R10 = f1.z, R11 = f1.w, R12 = f2.x;
        const float R20 = f2.y, R21 = f2.z, R22 = f2.w;
        float e[12];
#pragma unroll
        for (int s = 0; s < 4; ++s) {
            const u64 bits = __builtin_bit_cast(u64, kd[s]);
            const int j = (int)(bits & 0xFFFu);
            nbrs[qloc][h * 4 + s] = j;
            const float dx = xs[j] - mx;      // delta = nbr_center - center
            const float dy = ys[j] - my;
            const float dz = zs[j] - mz;
            e[s * 3 + 0] = dx * R00 + dy * R10 + dz * R20;
            e[s * 3 + 1] = dx * R01 + dy * R11 + dz * R21;
            e[s * 3 + 2] = dx * R02 + dy * R12 + dz * R22;
        }
        float4* eo = (float4*)(out_e + gq * 48 + h * 12);
        float4 v0 = {e[0], e[1], e[2],  e[3]};
        float4 v1 = {e[4], e[5], e[6],  e[7]};
        float4 v2 = {e[8], e[9], e[10], e[11]};
        eo[0] = v0; eo[1] = v1; eo[2] = v2;
    }

    // ---- fused gather (per wave: its 8 queries x 16 nbrs x 32 float4) ----
    const float4* ab = attr4 + (((size_t)b) << 12) * 32;
    const int wv = tid >> 6, lane = tid & 63;    // wv = 0..7
    const size_t obase = ((size_t)b * LQ + (size_t)qblk * QPB + (size_t)wv * 8) * 512;
#pragma unroll 4
    for (int it = 0; it < 64; ++it) {
        const int idx = it * 64 + lane;      // 0..4095
        const int qw  = idx >> 9;            // 0..7 within-wave query
        const int r   = idx & 511;
        const int k   = r >> 5, d4 = r & 31;
        const int nb  = nbrs[wv * 8 + qw][k];
        const float4 v = ab[(size_t)nb * 32 + d4];
        nfloat4 nv = {v.x, v.y, v.z, v.w};
        __builtin_nontemporal_store(nv, &outg4[obase + idx]);
    }
}

extern "C" void kernel_launch(void* const* d_in, const int* in_sizes, int n_in,
                              void* d_out, int out_size, void* d_ws, size_t ws_size,
                              hipStream_t stream)
{
    const float* frame = (const float*)d_in[0];   // (8,4096,4,3) f32
    const float* attr  = (const float*)d_in[1];   // (8,4096,128) f32
    float* out = (float*)d_out;                   // euclidian ++ gathered

    nfloat4* outg4 = (nfloat4*)(out + (size_t)BQ * LQ * KNB * 3);
    knn_fused_kernel<<<BQ * BPB, TPB, 0, stream>>>(
        (const float4*)frame, (const float4*)attr, out, outg4);
}